// Round 2
// baseline (49.291 us; speedup 1.0000x reference)
//
#include <hip/hip_runtime.h>
#include <hip/hip_bf16.h>

// Problem constants (from reference)
#define NN     6400   // total nodes
#define NG     200    // nodes per graph
#define NB     32     // graphs (NN/NG)
#define F      128    // F_in == F_out == 128
#define R      8      // output rows per block
#define SLABS  (NG / R)   // 25 slabs per graph -> 800 blocks total

// ---------------------------------------------------------------------------
// Fused kernel. Uses associativity:
//   out_b = (sigmoid(adj_bb) * mask) @ (feat_b @ W)
//         = ((sigmoid(adj_bb) * mask) @ feat_b) @ W
// so each 8-row slab of each graph is fully independent:
//   Phase A: build M_slab = sigmoid(adj) * (0.5(R+R^T)+I)   [8 x 200] in LDS
//   Phase B: T = M_slab @ feat_b                            [8 x 128] in LDS
//   Phase C: out_slab = T @ W                               [8 x 128] to global
// 256 threads: thread -> (row r0 = t>>5 in [0,8), col4 c0 = (t&31)*4).
// ---------------------------------------------------------------------------
__global__ __launch_bounds__(256) void fused_graphconv_kernel(
    const float* __restrict__ adj,
    const float* __restrict__ rew,
    const float* __restrict__ feat,
    const float* __restrict__ weight,
    float* __restrict__ out)
{
    const int b    = blockIdx.x / SLABS;   // graph
    const int slab = blockIdx.x % SLABS;
    const int i0   = slab * R;             // local row offset in graph
    const int t    = threadIdx.x;

    __shared__ float sM[R][NG];   // 8*200*4 = 6.4 KB
    __shared__ float sT[R][F];    // 8*128*4 = 4.0 KB

    // ---- Phase A: masked matrix rows [i0, i0+8) x [0,200) ----
    for (int idx = t; idx < R * NG; idx += 256) {
        const int i  = idx / NG;
        const int j  = idx - i * NG;
        const int gi = i0 + i;
        const float a = adj[(size_t)(b * NG + gi) * NN + (size_t)(b * NG + j)];
        const float s = 1.0f / (1.0f + __expf(-a));
        const float m = 0.5f * (rew[gi * NG + j] + rew[j * NG + gi]) +
                        (gi == j ? 1.0f : 0.0f);
        sM[i][j] = s * m;
    }
    __syncthreads();

    const int r0 = t >> 5;         // row within slab [0,8)
    const int c0 = (t & 31) * 4;   // col group [0,128) step 4

    // ---- Phase B: T[r0][c0..c0+3] = sum_j M[r0][j] * feat_b[j][c0..c0+3] ----
    const float* __restrict__ Fb = feat + (size_t)b * NG * F;
    float4 acc = make_float4(0.f, 0.f, 0.f, 0.f);
#pragma unroll 4
    for (int j = 0; j < NG; ++j) {
        const float  m  = sM[r0][j];
        const float4 f4 = *(const float4*)&Fb[(size_t)j * F + c0];
        acc.x += m * f4.x;
        acc.y += m * f4.y;
        acc.z += m * f4.z;
        acc.w += m * f4.w;
    }
    *(float4*)&sT[r0][c0] = acc;
    __syncthreads();

    // ---- Phase C: out[r0][c0..c0+3] = sum_k T[r0][k] * W[k][c0..c0+3] ----
    float4 o = make_float4(0.f, 0.f, 0.f, 0.f);
#pragma unroll 4
    for (int k = 0; k < F; ++k) {
        const float  tv = sT[r0][k];
        const float4 w4 = *(const float4*)&weight[k * F + c0];
        o.x += tv * w4.x;
        o.y += tv * w4.y;
        o.z += tv * w4.z;
        o.w += tv * w4.w;
    }
    *(float4*)&out[(size_t)(b * NG + i0 + r0) * F + c0] = o;
}

// ---------------------------------------------------------------------------
extern "C" void kernel_launch(void* const* d_in, const int* in_sizes, int n_in,
                              void* d_out, int out_size, void* d_ws, size_t ws_size,
                              hipStream_t stream)
{
    const float* adj    = (const float*)d_in[0];  // [6400, 6400]
    const float* feat   = (const float*)d_in[1];  // [6400, 128]
    const float* weight = (const float*)d_in[2];  // [128, 128]
    const float* rew    = (const float*)d_in[3];  // [200, 200]
    float*       out    = (float*)d_out;          // [6400, 128]

    fused_graphconv_kernel<<<NB * SLABS, 256, 0, stream>>>(adj, rew, feat, weight, out);
}

// Round 3
// 14.932 us; speedup vs baseline: 3.3011x; 3.3011x over previous
//
#include <hip/hip_runtime.h>
#include <hip/hip_bf16.h>

#define NN 6400   // total nodes
#define NG 200    // nodes per graph
#define NB 32     // graphs
#define FF 128    // F_in == F_out

typedef __attribute__((ext_vector_type(8))) short s8v;  // 8 x bf16 (4 VGPRs)
typedef __attribute__((ext_vector_type(4))) float f4v;  // MFMA accumulator

__device__ __forceinline__ short f2bf(float x) {
  unsigned u = __float_as_uint(x);
  u += 0x7FFFu + ((u >> 16) & 1u);   // RNE
  return (short)(u >> 16);
}

// Bank-swizzle for LDS fragment granules (bijective per 64-granule tile).
__device__ __forceinline__ int swz(int g) {
  return g ^ ((g >> 4) & 3) ^ ((g >> 6) & 7);
}

// support fragment layout: [b][kc=7][nt=8][lane=64][e=8] bf16 (K padded to 224)
__device__ __forceinline__ size_t supp_elem(int b, int kloc, int n) {
  return ((((size_t)b * 7 + (kloc >> 5)) * 8 + (n >> 4)) * 64
          + (n & 15) + ((kloc >> 3) & 3) * 16) * 8 + (kloc & 7);
}

// ---------------------------------------------------------------------------
// K1: blocks 0..199: msk row + support = feat @ W (MFMA) -> bf16 B-frags in ws
//     blocks 200..231: zero-fill K-pad (k=200..223) fragment slots for graph b
// ---------------------------------------------------------------------------
__global__ __launch_bounds__(256) void prep_kernel(
    const float* __restrict__ feat, const float* __restrict__ weight,
    const float* __restrict__ rew, float* __restrict__ msk,
    short* __restrict__ supp)
{
  const int t = threadIdx.x;
  const int bid = blockIdx.x;

  if (bid >= 200) {                      // ---- K-pad zero-fill ----
    const int b = bid - 200;
    const size_t base = (((size_t)b * 7 + 6) * 8) * 512;  // shorts, [b][kc=6][0][0][0]
    for (int q = t; q < 1536; q += 256) {                 // 3072 shorts = 1536 dwords
      const int nt = q / 192, p = q - nt * 192;
      unsigned* dst = (unsigned*)(supp + base + (size_t)nt * 512 + 128) + p;
      *dst = 0u;
    }
    return;
  }

  __shared__ s8v sW[2048];   // W B-frags [kc=4][nt=8][lane=64], 32 KB

  // ---- msk row r = bid: 0.5(R+R^T)+I, zero-padded to 224 cols ----
  {
    const int r = bid;
    if (t < 224) {
      float v = 0.f;
      if (t < 200)
        v = 0.5f * (rew[r * NG + t] + rew[t * NG + r]) + (r == t ? 1.f : 0.f);
      msk[r * 224 + t] = v;
    }
  }

  // ---- stage W fragments: thread handles (kg, n): k = kg*8+e ----
  for (int p = 0; p < 8; ++p) {
    const int idx = t + p * 256;            // < 2048
    const int n = idx & 127, kg = idx >> 7; // kg 0..15
    s8v v;
#pragma unroll
    for (int e = 0; e < 8; ++e)
      v[e] = f2bf(weight[(kg * 8 + e) * FF + n]);
    sW[((kg >> 2) * 8 + (n >> 4)) * 64 + (n & 15) + (kg & 3) * 16] = v;
  }
  __syncthreads();

  // ---- support rows bid*32 .. +31 via MFMA ----
  const int w = t >> 6, l = t & 63;
  const int mt = w >> 1, nh = w & 1;
  const int arow = bid * 32 + mt * 16 + (l & 15);
  const int klane = (l >> 4) * 8;

  f4v acc0 = {0.f,0.f,0.f,0.f}, acc1 = acc0, acc2 = acc0, acc3 = acc0;
#pragma unroll
  for (int kc = 0; kc < 4; ++kc) {
    const float* fp = feat + (size_t)arow * FF + kc * 32 + klane;
    const float4 fa = *(const float4*)fp;
    const float4 fb = *(const float4*)(fp + 4);
    s8v af;
    af[0]=f2bf(fa.x); af[1]=f2bf(fa.y); af[2]=f2bf(fa.z); af[3]=f2bf(fa.w);
    af[4]=f2bf(fb.x); af[5]=f2bf(fb.y); af[6]=f2bf(fb.z); af[7]=f2bf(fb.w);
    acc0 = __builtin_amdgcn_mfma_f32_16x16x32_bf16(af, sW[(kc*8 + nh*4 + 0)*64 + l], acc0, 0,0,0);
    acc1 = __builtin_amdgcn_mfma_f32_16x16x32_bf16(af, sW[(kc*8 + nh*4 + 1)*64 + l], acc1, 0,0,0);
    acc2 = __builtin_amdgcn_mfma_f32_16x16x32_bf16(af, sW[(kc*8 + nh*4 + 2)*64 + l], acc2, 0,0,0);
    acc3 = __builtin_amdgcn_mfma_f32_16x16x32_bf16(af, sW[(kc*8 + nh*4 + 3)*64 + l], acc3, 0,0,0);
  }

  // ---- scatter-store acc as bf16 B-fragments (D: col=l&15, row=(l>>4)*4+reg) ----
#pragma unroll
  for (int reg = 0; reg < 4; ++reg) {
    const int rr = bid * 32 + mt * 16 + (l >> 4) * 4 + reg;
    const unsigned bb = (unsigned)rr / 200u;
    const int kloc = rr - (int)bb * 200;
    const int n0 = nh * 64 + (l & 15);
    supp[supp_elem(bb, kloc, n0)]      = f2bf(acc0[reg]);
    supp[supp_elem(bb, kloc, n0 + 16)] = f2bf(acc1[reg]);
    supp[supp_elem(bb, kloc, n0 + 32)] = f2bf(acc2[reg]);
    supp[supp_elem(bb, kloc, n0 + 48)] = f2bf(acc3[reg]);
  }
}

// ---------------------------------------------------------------------------
// K2: out_b = (sigmoid(adj_bb) * msk) @ support_b   via MFMA.
// 256 blocks = 32 graphs x 8 slabs (25 rows stored, 32 computed).
// ---------------------------------------------------------------------------
__global__ __launch_bounds__(256) void graphconv_kernel(
    const float* __restrict__ adj, const float* __restrict__ msk,
    const short* __restrict__ supp, float* __restrict__ out)
{
  __shared__ s8v sM[896];   // M A-frags [mt=2][kc=7][lane=64], swizzled, 14 KB
  const int t = threadIdx.x;
  const int sw = (blockIdx.x & 7) * 32 + (blockIdx.x >> 3);  // colocate slabs per XCD
  const int b = sw >> 3, slab = sw & 7;
  const int i0 = slab * 25;

  // ---- Phase A: build M fragments (rows>=200 or cols>=200 -> 0) ----
#pragma unroll
  for (int p = 0; p < 4; ++p) {
    const int idx = t + p * 256;
    if (idx < 896) {                      // 32 rows x 28 j-groups
      const int i = idx / 28, jg = idx - i * 28;
      const int gi = i0 + i;
      s8v v = {0,0,0,0,0,0,0,0};
      if (jg < 25 && gi < 200) {
        const float* ap = adj + ((size_t)(b * NG + gi) * NN + b * NG + jg * 8);
        const float4 a0 = *(const float4*)ap;
        const float4 a1 = *(const float4*)(ap + 4);
        const float* mp = msk + gi * 224 + jg * 8;
        const float4 m0 = *(const float4*)mp;
        const float4 m1 = *(const float4*)(mp + 4);
        v[0] = f2bf(m0.x * __builtin_amdgcn_rcpf(1.f + __expf(-a0.x)));
        v[1] = f2bf(m0.y * __builtin_amdgcn_rcpf(1.f + __expf(-a0.y)));
        v[2] = f2bf(m0.z * __builtin_amdgcn_rcpf(1.f + __expf(-a0.z)));
        v[3] = f2bf(m0.w * __builtin_amdgcn_rcpf(1.f + __expf(-a0.w)));
        v[4] = f2bf(m1.x * __builtin_amdgcn_rcpf(1.f + __expf(-a1.x)));
        v[5] = f2bf(m1.y * __builtin_amdgcn_rcpf(1.f + __expf(-a1.y)));
        v[6] = f2bf(m1.z * __builtin_amdgcn_rcpf(1.f + __expf(-a1.z)));
        v[7] = f2bf(m1.w * __builtin_amdgcn_rcpf(1.f + __expf(-a1.w)));
      }
      const int g = ((i >> 4) * 7 + (jg >> 2)) * 64 + (i & 15) + (jg & 3) * 16;
      sM[swz(g)] = v;
    }
  }
  __syncthreads();

  // ---- Phase B: 7 K-chunks x 4 N-tiles of MFMA ----
  const int w = t >> 6, l = t & 63;
  const int mt = w >> 1, nh = w & 1;
  const s8v* sb = (const s8v*)(supp + (size_t)b * 7 * 8 * 512);  // [kc][nt][lane]

  f4v acc0 = {0.f,0.f,0.f,0.f}, acc1 = acc0, acc2 = acc0, acc3 = acc0;
#pragma unroll
  for (int kc = 0; kc < 7; ++kc) {
    const s8v af = sM[swz((mt * 7 + kc) * 64 + l)];
    acc0 = __builtin_amdgcn_mfma_f32_16x16x32_bf16(af, sb[(kc*8 + nh*4 + 0)*64 + l], acc0, 0,0,0);
    acc1 = __builtin_amdgcn_mfma_f32_16x16x32_bf16(af, sb[(kc*8 + nh*4 + 1)*64 + l], acc1, 0,0,0);
    acc2 = __builtin_amdgcn_mfma_f32_16x16x32_bf16(af, sb[(kc*8 + nh*4 + 2)*64 + l], acc2, 0,0,0);
    acc3 = __builtin_amdgcn_mfma_f32_16x16x32_bf16(af, sb[(kc*8 + nh*4 + 3)*64 + l], acc3, 0,0,0);
  }

  // ---- store (guard: only first 25 computed rows are real) ----
#pragma unroll
  for (int reg = 0; reg < 4; ++reg) {
    const int rl = mt * 16 + (l >> 4) * 4 + reg;
    if (rl < 25) {
      const size_t o = (size_t)(b * NG + i0 + rl) * FF + nh * 64 + (l & 15);
      out[o]      = acc0[reg];
      out[o + 16] = acc1[reg];
      out[o + 32] = acc2[reg];
      out[o + 48] = acc3[reg];
    }
  }
}

// ---------------------------------------------------------------------------
extern "C" void kernel_launch(void* const* d_in, const int* in_sizes, int n_in,
                              void* d_out, int out_size, void* d_ws, size_t ws_size,
                              hipStream_t stream)
{
  const float* adj    = (const float*)d_in[0];  // [6400, 6400]
  const float* feat   = (const float*)d_in[1];  // [6400, 128]
  const float* weight = (const float*)d_in[2];  // [128, 128]
  const float* rew    = (const float*)d_in[3];  // [200, 200]
  float*       out    = (float*)d_out;          // [6400, 128]

  short* supp = (short*)d_ws;                          // 1,835,008 B bf16 frags
  float* msk  = (float*)((char*)d_ws + 1835008);       // [200][224] fp32

  prep_kernel<<<232, 256, 0, stream>>>(feat, weight, rew, msk, supp);
  graphconv_kernel<<<256, 256, 0, stream>>>(adj, msk, supp, out);
}